// Round 1
// baseline (147.143 us; speedup 1.0000x reference)
//
#include <hip/hip_runtime.h>

// MaskedDenseMatMul: out[b,h,q,k] = (sum_d a[b,h,q,d]*b[b,h,k,d]) * mask[b,0,q,k]
// B=2 H=8 S=2048 D=64, fp32 in/out. Memory-bound on the 256 MiB output write.
// Strategy: bf16 MFMA (16x16x32), fragments loaded straight from global
// (A/B are L2-resident), mask fused in epilogue.

typedef __attribute__((ext_vector_type(8))) short bf16x8;
typedef __attribute__((ext_vector_type(4))) float f32x4;

static constexpr int S = 2048;
static constexpr int D = 64;

__device__ inline short f2bf(float f) {
    // round-to-nearest-even fp32 -> bf16 (inputs are finite normals; no NaN path)
    union { float f; unsigned u; } v; v.f = f;
    unsigned r = (v.u + 0x7FFFu + ((v.u >> 16) & 1u)) >> 16;
    return (short)r;
}

__global__ __launch_bounds__(256) void masked_mm_kernel(
    const float* __restrict__ A,
    const float* __restrict__ B,
    const float* __restrict__ M,
    float* __restrict__ O) {

    const int bh = blockIdx.z;          // 0..15 ; b = bh>>3, h = bh&7
    const int bb = bh >> 3;
    const int lane = threadIdx.x & 63;
    const int w    = threadIdx.x >> 6;  // wave 0..3
    const int wr = w >> 1, wc = w & 1;  // 2x2 wave grid

    const int r0 = blockIdx.y * 64 + wr * 32;   // output row base for this wave
    const int c0 = blockIdx.x * 64 + wc * 32;   // output col base for this wave

    const float* __restrict__ Ab = A + (size_t)bh * S * D;
    const float* __restrict__ Bb = B + (size_t)bh * S * D;
    const float* __restrict__ Mb = M + (size_t)bb * S * S;
    float* __restrict__ Ob       = O + (size_t)bh * S * S;

    const int rlane = lane & 15;   // row (A) / col (B) within 16
    const int kg    = lane >> 4;   // k-group 0..3 (8 elems each)

    // ---- load fragments straight from global, fp32 -> bf16 ----
    bf16x8 af[2][2];  // [row-block][k-half]
    bf16x8 bfr[2][2]; // [col-block][k-half]
#pragma unroll
    for (int rb = 0; rb < 2; ++rb) {
#pragma unroll
        for (int kh = 0; kh < 2; ++kh) {
            const float* pa = Ab + (size_t)(r0 + rb * 16 + rlane) * D + kh * 32 + kg * 8;
            f32x4 f0 = *(const f32x4*)pa;
            f32x4 f1 = *(const f32x4*)(pa + 4);
            bf16x8 t;
            t[0] = f2bf(f0[0]); t[1] = f2bf(f0[1]); t[2] = f2bf(f0[2]); t[3] = f2bf(f0[3]);
            t[4] = f2bf(f1[0]); t[5] = f2bf(f1[1]); t[6] = f2bf(f1[2]); t[7] = f2bf(f1[3]);
            af[rb][kh] = t;

            const float* pb = Bb + (size_t)(c0 + rb * 16 + rlane) * D + kh * 32 + kg * 8;
            f32x4 g0 = *(const f32x4*)pb;
            f32x4 g1 = *(const f32x4*)(pb + 4);
            bf16x8 u;
            u[0] = f2bf(g0[0]); u[1] = f2bf(g0[1]); u[2] = f2bf(g0[2]); u[3] = f2bf(g0[3]);
            u[4] = f2bf(g1[0]); u[5] = f2bf(g1[1]); u[6] = f2bf(g1[2]); u[7] = f2bf(g1[3]);
            bfr[rb][kh] = u;
        }
    }

    // ---- MFMA: acc[rb][cb] over K=64 (two K=32 steps) ----
    f32x4 acc[2][2];
#pragma unroll
    for (int rb = 0; rb < 2; ++rb)
#pragma unroll
        for (int cb = 0; cb < 2; ++cb) {
            f32x4 z = {0.f, 0.f, 0.f, 0.f};
            z = __builtin_amdgcn_mfma_f32_16x16x32_bf16(af[rb][0], bfr[cb][0], z, 0, 0, 0);
            z = __builtin_amdgcn_mfma_f32_16x16x32_bf16(af[rb][1], bfr[cb][1], z, 0, 0, 0);
            acc[rb][cb] = z;
        }

    // ---- epilogue: multiply by mask, store fp32 ----
    // C/D layout: col = lane&15, row = (lane>>4)*4 + j   [measured m89/m91]
#pragma unroll
    for (int rb = 0; rb < 2; ++rb) {
#pragma unroll
        for (int j = 0; j < 4; ++j) {
            const int r = r0 + rb * 16 + kg * 4 + j;
            const size_t rowoff = (size_t)r * S;
#pragma unroll
            for (int cb = 0; cb < 2; ++cb) {
                const int c = c0 + cb * 16 + rlane;
                const size_t idx = rowoff + c;
                Ob[idx] = acc[rb][cb][j] * Mb[idx];
            }
        }
    }
}

extern "C" void kernel_launch(void* const* d_in, const int* in_sizes, int n_in,
                              void* d_out, int out_size, void* d_ws, size_t ws_size,
                              hipStream_t stream) {
    const float* a = (const float*)d_in[0];
    const float* b = (const float*)d_in[1];
    const float* m = (const float*)d_in[2];
    float* o = (float*)d_out;

    dim3 grid(S / 64, S / 64, 16);  // (col tiles, row tiles, b*h)
    dim3 block(256);
    hipLaunchKernelGGL(masked_mm_kernel, grid, block, 0, stream, a, b, m, o);
}

// Round 2
// 117.387 us; speedup vs baseline: 1.2535x; 1.2535x over previous
//
#include <hip/hip_runtime.h>

// MaskedDenseMatMul: out[b,h,q,k] = (sum_d a[b,h,q,d]*b[b,h,k,d]) * mask[b,0,q,k]
// B=2 H=8 S=2048 D=64, fp32 in/out.  Memory-bound on the 256 MiB output write.
//
// R2 design:
//  - pre-pass converts A,B fp32->bf16 into d_ws (removes ~350 VALU ops/thread
//    from the main kernel's critical path)
//  - main kernel: grid z = b only; the 8 heads are looped INSIDE the block so
//    the mask tile is loaded once into registers (mask HBM = exactly 32 MiB)
//  - MFMA operands SWAPPED: mfma(B_frag, A_frag) -> lane holds 4 consecutive
//    output COLUMNS of one row -> float4 mask loads + float4 stores

typedef __attribute__((ext_vector_type(8))) short bf16x8;
typedef __attribute__((ext_vector_type(4))) float f32x4;

static constexpr int S = 2048;
static constexpr int D = 64;
static constexpr size_t NELEM = (size_t)16 * S * D;  // elems per input (B*H*S*D)

__device__ inline short f2bf(float f) {
    // round-to-nearest-even fp32 -> bf16
    union { float f; unsigned u; } v; v.f = f;
    unsigned r = (v.u + 0x7FFFu + ((v.u >> 16) & 1u)) >> 16;
    return (short)r;
}

// ---------------- conversion pre-pass: fp32 -> bf16, 8 elems/thread ----------
__global__ __launch_bounds__(256) void cvt_bf16_kernel(const float* __restrict__ src,
                                                       short* __restrict__ dst) {
    size_t i = ((size_t)blockIdx.x * 256 + threadIdx.x) * 8;
    f32x4 f0 = *(const f32x4*)(src + i);
    f32x4 f1 = *(const f32x4*)(src + i + 4);
    bf16x8 t;
    t[0] = f2bf(f0[0]); t[1] = f2bf(f0[1]); t[2] = f2bf(f0[2]); t[3] = f2bf(f0[3]);
    t[4] = f2bf(f1[0]); t[5] = f2bf(f1[1]); t[6] = f2bf(f1[2]); t[7] = f2bf(f1[3]);
    *(bf16x8*)(dst + i) = t;
}

// ---------------- main kernel (bf16 inputs from workspace) -------------------
__global__ __launch_bounds__(256) void masked_mm_bf16_kernel(
    const short* __restrict__ A16,
    const short* __restrict__ B16,
    const float* __restrict__ M,
    float* __restrict__ O) {

    const int bb   = blockIdx.z;            // batch 0..1
    const int lane = threadIdx.x & 63;
    const int w    = threadIdx.x >> 6;      // wave 0..3
    const int wr = w >> 1, wc = w & 1;      // 2x2 wave grid, 32x32 tile each

    const int r0 = blockIdx.y * 64 + wr * 32;
    const int c0 = blockIdx.x * 64 + wc * 32;

    const int rlane = lane & 15;            // operand-row within 16
    const int kg    = lane >> 4;            // k-group 0..3

    const float* __restrict__ Mb = M + (size_t)bb * S * S;

    // ---- mask tile: held in registers across all 8 heads ----
    // swapped-mfma C/D layout: acc[rb][cb][j] = O[r0+rb*16+rlane][c0+cb*16+kg*4+j]
    f32x4 mk[2][2];
#pragma unroll
    for (int rb = 0; rb < 2; ++rb)
#pragma unroll
        for (int cb = 0; cb < 2; ++cb)
            mk[rb][cb] = *(const f32x4*)(Mb + (size_t)(r0 + rb * 16 + rlane) * S
                                            + c0 + cb * 16 + kg * 4);

#pragma unroll 1
    for (int h = 0; h < 8; ++h) {
        const int bh = bb * 8 + h;
        const short* __restrict__ Ab = A16 + (size_t)bh * S * D;
        const short* __restrict__ Bb = B16 + (size_t)bh * S * D;

        bf16x8 af[2][2], bfr[2][2];
#pragma unroll
        for (int rb = 0; rb < 2; ++rb)
#pragma unroll
            for (int kh = 0; kh < 2; ++kh) {
                af[rb][kh]  = *(const bf16x8*)(Ab + (size_t)(r0 + rb * 16 + rlane) * D
                                                  + kh * 32 + kg * 8);
                bfr[rb][kh] = *(const bf16x8*)(Bb + (size_t)(c0 + rb * 16 + rlane) * D
                                                  + kh * 32 + kg * 8);
            }

        f32x4 acc[2][2];
#pragma unroll
        for (int rb = 0; rb < 2; ++rb)
#pragma unroll
            for (int cb = 0; cb < 2; ++cb) {
                f32x4 z = {0.f, 0.f, 0.f, 0.f};
                // SWAPPED operands: output "row" dim = B-rows (out col),
                // output "col" dim = A-rows (out row) -> lane holds 4 consec cols
                z = __builtin_amdgcn_mfma_f32_16x16x32_bf16(bfr[cb][0], af[rb][0], z, 0, 0, 0);
                z = __builtin_amdgcn_mfma_f32_16x16x32_bf16(bfr[cb][1], af[rb][1], z, 0, 0, 0);
                acc[rb][cb] = z;
            }

        float* __restrict__ Ob = O + (size_t)bh * S * S;
#pragma unroll
        for (int rb = 0; rb < 2; ++rb)
#pragma unroll
            for (int cb = 0; cb < 2; ++cb) {
                f32x4 v;
                v[0] = acc[rb][cb][0] * mk[rb][cb][0];
                v[1] = acc[rb][cb][1] * mk[rb][cb][1];
                v[2] = acc[rb][cb][2] * mk[rb][cb][2];
                v[3] = acc[rb][cb][3] * mk[rb][cb][3];
                *(f32x4*)(Ob + (size_t)(r0 + rb * 16 + rlane) * S
                             + c0 + cb * 16 + kg * 4) = v;
            }
    }
}

// ---------------- fallback (ws too small): inline conversion -----------------
__global__ __launch_bounds__(256) void masked_mm_f32_kernel(
    const float* __restrict__ A,
    const float* __restrict__ B,
    const float* __restrict__ M,
    float* __restrict__ O) {

    const int bb   = blockIdx.z;
    const int lane = threadIdx.x & 63;
    const int w    = threadIdx.x >> 6;
    const int wr = w >> 1, wc = w & 1;
    const int r0 = blockIdx.y * 64 + wr * 32;
    const int c0 = blockIdx.x * 64 + wc * 32;
    const int rlane = lane & 15;
    const int kg    = lane >> 4;

    const float* __restrict__ Mb = M + (size_t)bb * S * S;
    f32x4 mk[2][2];
#pragma unroll
    for (int rb = 0; rb < 2; ++rb)
#pragma unroll
        for (int cb = 0; cb < 2; ++cb)
            mk[rb][cb] = *(const f32x4*)(Mb + (size_t)(r0 + rb * 16 + rlane) * S
                                            + c0 + cb * 16 + kg * 4);

#pragma unroll 1
    for (int h = 0; h < 8; ++h) {
        const int bh = bb * 8 + h;
        const float* __restrict__ Ab = A + (size_t)bh * S * D;
        const float* __restrict__ Bb = B + (size_t)bh * S * D;

        bf16x8 af[2][2], bfr[2][2];
#pragma unroll
        for (int rb = 0; rb < 2; ++rb)
#pragma unroll
            for (int kh = 0; kh < 2; ++kh) {
                const float* pa = Ab + (size_t)(r0 + rb * 16 + rlane) * D + kh * 32 + kg * 8;
                f32x4 f0 = *(const f32x4*)pa, f1 = *(const f32x4*)(pa + 4);
                bf16x8 t;
                t[0]=f2bf(f0[0]); t[1]=f2bf(f0[1]); t[2]=f2bf(f0[2]); t[3]=f2bf(f0[3]);
                t[4]=f2bf(f1[0]); t[5]=f2bf(f1[1]); t[6]=f2bf(f1[2]); t[7]=f2bf(f1[3]);
                af[rb][kh] = t;
                const float* pb = Bb + (size_t)(c0 + rb * 16 + rlane) * D + kh * 32 + kg * 8;
                f32x4 g0 = *(const f32x4*)pb, g1 = *(const f32x4*)(pb + 4);
                bf16x8 u;
                u[0]=f2bf(g0[0]); u[1]=f2bf(g0[1]); u[2]=f2bf(g0[2]); u[3]=f2bf(g0[3]);
                u[4]=f2bf(g1[0]); u[5]=f2bf(g1[1]); u[6]=f2bf(g1[2]); u[7]=f2bf(g1[3]);
                bfr[rb][kh] = u;
            }

        f32x4 acc[2][2];
#pragma unroll
        for (int rb = 0; rb < 2; ++rb)
#pragma unroll
            for (int cb = 0; cb < 2; ++cb) {
                f32x4 z = {0.f, 0.f, 0.f, 0.f};
                z = __builtin_amdgcn_mfma_f32_16x16x32_bf16(bfr[cb][0], af[rb][0], z, 0, 0, 0);
                z = __builtin_amdgcn_mfma_f32_16x16x32_bf16(bfr[cb][1], af[rb][1], z, 0, 0, 0);
                acc[rb][cb] = z;
            }

        float* __restrict__ Ob = O + (size_t)bh * S * S;
#pragma unroll
        for (int rb = 0; rb < 2; ++rb)
#pragma unroll
            for (int cb = 0; cb < 2; ++cb) {
                f32x4 v;
                v[0] = acc[rb][cb][0] * mk[rb][cb][0];
                v[1] = acc[rb][cb][1] * mk[rb][cb][1];
                v[2] = acc[rb][cb][2] * mk[rb][cb][2];
                v[3] = acc[rb][cb][3] * mk[rb][cb][3];
                *(f32x4*)(Ob + (size_t)(r0 + rb * 16 + rlane) * S
                             + c0 + cb * 16 + kg * 4) = v;
            }
    }
}

extern "C" void kernel_launch(void* const* d_in, const int* in_sizes, int n_in,
                              void* d_out, int out_size, void* d_ws, size_t ws_size,
                              hipStream_t stream) {
    const float* a = (const float*)d_in[0];
    const float* b = (const float*)d_in[1];
    const float* m = (const float*)d_in[2];
    float* o = (float*)d_out;

    dim3 grid(S / 64, S / 64, 2);   // (col tiles, row tiles, batch)
    dim3 block(256);

    const size_t ws_need = 2 * NELEM * sizeof(short);  // 8.4 MB
    if (ws_size >= ws_need) {
        short* a16 = (short*)d_ws;
        short* b16 = a16 + NELEM;
        const int cvt_blocks = (int)(NELEM / (256 * 8));  // exact: NELEM = 2^21
        hipLaunchKernelGGL(cvt_bf16_kernel, dim3(cvt_blocks), block, 0, stream, a, a16);
        hipLaunchKernelGGL(cvt_bf16_kernel, dim3(cvt_blocks), block, 0, stream, b, b16);
        hipLaunchKernelGGL(masked_mm_bf16_kernel, grid, block, 0, stream, a16, b16, m, o);
    } else {
        hipLaunchKernelGGL(masked_mm_f32_kernel, grid, block, 0, stream, a, b, m, o);
    }
}

// Round 3
// 108.011 us; speedup vs baseline: 1.3623x; 1.0868x over previous
//
#include <hip/hip_runtime.h>

// MaskedDenseMatMul: out[b,h,q,k] = (sum_d a[b,h,q,d]*b[b,h,k,d]) * mask[b,0,q,k]
// B=2 H=8 S=2048 D=64, fp32 in/out.  Memory-bound on the 256 MiB output write.
//
// R3 design:
//  - one cvt pre-pass converts A,B fp32->bf16 into d_ws
//  - grid z = 8 (2 heads per block) -> 8192 blocks: 4x parallelism for latency
//    hiding; mask tile still register-held across the block's 2 heads; the 4x
//    mask re-read across z-slices is L3-resident (64 MB << 256 MB)
//  - 2-head body fully unrolled -> both heads' loads/MFMAs interleave (ILP)
//  - nontemporal f32x4 stores: output is write-once, keep L2/L3 for mask+A/B
//  - swapped MFMA operands -> lane holds 4 consecutive output cols of one row
//    -> float4 mask loads + float4 stores

typedef __attribute__((ext_vector_type(8))) short bf16x8;
typedef __attribute__((ext_vector_type(4))) float f32x4;

static constexpr int S = 2048;
static constexpr int D = 64;
static constexpr size_t NELEM = (size_t)16 * S * D;  // elems per input

__device__ inline short f2bf(float f) {
    union { float f; unsigned u; } v; v.f = f;
    unsigned r = (v.u + 0x7FFFu + ((v.u >> 16) & 1u)) >> 16;
    return (short)r;
}

// ---------------- conversion pre-pass: both arrays in one launch -------------
__global__ __launch_bounds__(256) void cvt_bf16_kernel(const float* __restrict__ a,
                                                       const float* __restrict__ b,
                                                       short* __restrict__ a16,
                                                       short* __restrict__ b16) {
    const float* src = blockIdx.y ? b : a;
    short* dst       = blockIdx.y ? b16 : a16;
    size_t i = ((size_t)blockIdx.x * 256 + threadIdx.x) * 8;
    f32x4 f0 = *(const f32x4*)(src + i);
    f32x4 f1 = *(const f32x4*)(src + i + 4);
    bf16x8 t;
    t[0] = f2bf(f0[0]); t[1] = f2bf(f0[1]); t[2] = f2bf(f0[2]); t[3] = f2bf(f0[3]);
    t[4] = f2bf(f1[0]); t[5] = f2bf(f1[1]); t[6] = f2bf(f1[2]); t[7] = f2bf(f1[3]);
    *(bf16x8*)(dst + i) = t;
}

// ---------------- main kernel (bf16 inputs from workspace) -------------------
__global__ __launch_bounds__(256) void masked_mm_bf16_kernel(
    const short* __restrict__ A16,
    const short* __restrict__ B16,
    const float* __restrict__ M,
    float* __restrict__ O) {

    const int bb   = blockIdx.z >> 2;        // batch 0..1
    const int hp   = blockIdx.z & 3;         // head-pair 0..3
    const int lane = threadIdx.x & 63;
    const int w    = threadIdx.x >> 6;       // wave 0..3
    const int wr = w >> 1, wc = w & 1;       // 2x2 wave grid, 32x32 tile each

    const int r0 = blockIdx.y * 64 + wr * 32;
    const int c0 = blockIdx.x * 64 + wc * 32;

    const int rlane = lane & 15;             // operand-row within 16
    const int kg    = lane >> 4;             // k-group 0..3

    const float* __restrict__ Mb = M + (size_t)bb * S * S;

    // mask tile in registers, reused by both heads
    // swapped-mfma C/D layout: acc[rb][cb][j] = O[r0+rb*16+rlane][c0+cb*16+kg*4+j]
    f32x4 mk[2][2];
#pragma unroll
    for (int rb = 0; rb < 2; ++rb)
#pragma unroll
        for (int cb = 0; cb < 2; ++cb)
            mk[rb][cb] = *(const f32x4*)(Mb + (size_t)(r0 + rb * 16 + rlane) * S
                                            + c0 + cb * 16 + kg * 4);

#pragma unroll
    for (int h = 0; h < 2; ++h) {
        const int bh = bb * 8 + hp * 2 + h;
        const short* __restrict__ Ab = A16 + (size_t)bh * S * D;
        const short* __restrict__ Bb = B16 + (size_t)bh * S * D;

        bf16x8 af[2][2], bfr[2][2];
#pragma unroll
        for (int rb = 0; rb < 2; ++rb)
#pragma unroll
            for (int kh = 0; kh < 2; ++kh) {
                af[rb][kh]  = *(const bf16x8*)(Ab + (size_t)(r0 + rb * 16 + rlane) * D
                                                  + kh * 32 + kg * 8);
                bfr[rb][kh] = *(const bf16x8*)(Bb + (size_t)(c0 + rb * 16 + rlane) * D
                                                  + kh * 32 + kg * 8);
            }

        f32x4 acc[2][2];
#pragma unroll
        for (int rb = 0; rb < 2; ++rb)
#pragma unroll
            for (int cb = 0; cb < 2; ++cb) {
                f32x4 z = {0.f, 0.f, 0.f, 0.f};
                // SWAPPED operands: lane holds 4 consecutive out-cols of one row
                z = __builtin_amdgcn_mfma_f32_16x16x32_bf16(bfr[cb][0], af[rb][0], z, 0, 0, 0);
                z = __builtin_amdgcn_mfma_f32_16x16x32_bf16(bfr[cb][1], af[rb][1], z, 0, 0, 0);
                acc[rb][cb] = z;
            }

        float* __restrict__ Ob = O + (size_t)bh * S * S;
#pragma unroll
        for (int rb = 0; rb < 2; ++rb)
#pragma unroll
            for (int cb = 0; cb < 2; ++cb) {
                f32x4 v;
                v[0] = acc[rb][cb][0] * mk[rb][cb][0];
                v[1] = acc[rb][cb][1] * mk[rb][cb][1];
                v[2] = acc[rb][cb][2] * mk[rb][cb][2];
                v[3] = acc[rb][cb][3] * mk[rb][cb][3];
                __builtin_nontemporal_store(v,
                    (f32x4*)(Ob + (size_t)(r0 + rb * 16 + rlane) * S
                                + c0 + cb * 16 + kg * 4));
            }
    }
}

// ---------------- fallback (ws too small): inline conversion -----------------
__global__ __launch_bounds__(256) void masked_mm_f32_kernel(
    const float* __restrict__ A,
    const float* __restrict__ B,
    const float* __restrict__ M,
    float* __restrict__ O) {

    const int bb   = blockIdx.z >> 2;
    const int hp   = blockIdx.z & 3;
    const int lane = threadIdx.x & 63;
    const int w    = threadIdx.x >> 6;
    const int wr = w >> 1, wc = w & 1;
    const int r0 = blockIdx.y * 64 + wr * 32;
    const int c0 = blockIdx.x * 64 + wc * 32;
    const int rlane = lane & 15;
    const int kg    = lane >> 4;

    const float* __restrict__ Mb = M + (size_t)bb * S * S;
    f32x4 mk[2][2];
#pragma unroll
    for (int rb = 0; rb < 2; ++rb)
#pragma unroll
        for (int cb = 0; cb < 2; ++cb)
            mk[rb][cb] = *(const f32x4*)(Mb + (size_t)(r0 + rb * 16 + rlane) * S
                                            + c0 + cb * 16 + kg * 4);

#pragma unroll
    for (int h = 0; h < 2; ++h) {
        const int bh = bb * 8 + hp * 2 + h;
        const float* __restrict__ Ab = A + (size_t)bh * S * D;
        const float* __restrict__ Bb = B + (size_t)bh * S * D;

        bf16x8 af[2][2], bfr[2][2];
#pragma unroll
        for (int rb = 0; rb < 2; ++rb)
#pragma unroll
            for (int kh = 0; kh < 2; ++kh) {
                const float* pa = Ab + (size_t)(r0 + rb * 16 + rlane) * D + kh * 32 + kg * 8;
                f32x4 f0 = *(const f32x4*)pa, f1 = *(const f32x4*)(pa + 4);
                bf16x8 t;
                t[0]=f2bf(f0[0]); t[1]=f2bf(f0[1]); t[2]=f2bf(f0[2]); t[3]=f2bf(f0[3]);
                t[4]=f2bf(f1[0]); t[5]=f2bf(f1[1]); t[6]=f2bf(f1[2]); t[7]=f2bf(f1[3]);
                af[rb][kh] = t;
                const float* pb = Bb + (size_t)(c0 + rb * 16 + rlane) * D + kh * 32 + kg * 8;
                f32x4 g0 = *(const f32x4*)pb, g1 = *(const f32x4*)(pb + 4);
                bf16x8 u;
                u[0]=f2bf(g0[0]); u[1]=f2bf(g0[1]); u[2]=f2bf(g0[2]); u[3]=f2bf(g0[3]);
                u[4]=f2bf(g1[0]); u[5]=f2bf(g1[1]); u[6]=f2bf(g1[2]); u[7]=f2bf(g1[3]);
                bfr[rb][kh] = u;
            }

        f32x4 acc[2][2];
#pragma unroll
        for (int rb = 0; rb < 2; ++rb)
#pragma unroll
            for (int cb = 0; cb < 2; ++cb) {
                f32x4 z = {0.f, 0.f, 0.f, 0.f};
                z = __builtin_amdgcn_mfma_f32_16x16x32_bf16(bfr[cb][0], af[rb][0], z, 0, 0, 0);
                z = __builtin_amdgcn_mfma_f32_16x16x32_bf16(bfr[cb][1], af[rb][1], z, 0, 0, 0);
                acc[rb][cb] = z;
            }

        float* __restrict__ Ob = O + (size_t)bh * S * S;
#pragma unroll
        for (int rb = 0; rb < 2; ++rb)
#pragma unroll
            for (int cb = 0; cb < 2; ++cb) {
                f32x4 v;
                v[0] = acc[rb][cb][0] * mk[rb][cb][0];
                v[1] = acc[rb][cb][1] * mk[rb][cb][1];
                v[2] = acc[rb][cb][2] * mk[rb][cb][2];
                v[3] = acc[rb][cb][3] * mk[rb][cb][3];
                __builtin_nontemporal_store(v,
                    (f32x4*)(Ob + (size_t)(r0 + rb * 16 + rlane) * S
                                + c0 + cb * 16 + kg * 4));
            }
    }
}

extern "C" void kernel_launch(void* const* d_in, const int* in_sizes, int n_in,
                              void* d_out, int out_size, void* d_ws, size_t ws_size,
                              hipStream_t stream) {
    const float* a = (const float*)d_in[0];
    const float* b = (const float*)d_in[1];
    const float* m = (const float*)d_in[2];
    float* o = (float*)d_out;

    dim3 grid(S / 64, S / 64, 8);   // (col tiles, row tiles, batch*head-pair)
    dim3 block(256);

    const size_t ws_need = 2 * NELEM * sizeof(short);  // 8.4 MB
    if (ws_size >= ws_need) {
        short* a16 = (short*)d_ws;
        short* b16 = a16 + NELEM;
        const int cvt_blocks = (int)(NELEM / (256 * 8));  // 1024
        hipLaunchKernelGGL(cvt_bf16_kernel, dim3(cvt_blocks, 2), block, 0, stream,
                           a, b, a16, b16);
        hipLaunchKernelGGL(masked_mm_bf16_kernel, grid, block, 0, stream, a16, b16, m, o);
    } else {
        hipLaunchKernelGGL(masked_mm_f32_kernel, grid, block, 0, stream, a, b, m, o);
    }
}